// Round 2
// baseline (37.429 us; speedup 1.0000x reference)
//
#include <hip/hip_runtime.h>
#include <math.h>

#define B_ 8
#define U_ 512
#define T_ 1024
#define H_ 512
#define D_ 128
#define K_ 10

#define UT 8      // u rows per block (kernel 3)
#define TC 64     // t chunk size
#define AT_THREADS 128

// ---------------- Kernel 0: repack W into interleaved-transposed layout ----
// Wt4[hh4*30 + j] = float4{ W[4*hh4+0][j], W[4*hh4+1][j], W[4*hh4+2][j], W[4*hh4+3][j] }
__global__ __launch_bounds__(256)
void wtrans_kernel(const float* __restrict__ W, float4* __restrict__ Wt4) {
    int idx = blockIdx.x * 256 + threadIdx.x;      // 0 .. 128*30-1
    if (idx >= (H_ / 4) * 3 * K_) return;
    int hh4 = idx / (3 * K_), j = idx % (3 * K_);
    float4 v;
    v.x = W[(4 * hh4 + 0) * 3 * K_ + j];
    v.y = W[(4 * hh4 + 1) * 3 * K_ + j];
    v.z = W[(4 * hh4 + 2) * 3 * K_ + j];
    v.w = W[(4 * hh4 + 3) * 3 * K_ + j];
    Wt4[idx] = v;
}

// ---------------- Kernel 1: p = exp(h_t @ W + b) -----------------
// One wave per (b,u) row; lane j < 30 computes output col j.
// h loads are wave-uniform (scalarizable); W loads are coalesced float4.
__global__ __launch_bounds__(64)
void params_kernel(const float* __restrict__ h_t,
                   const float4* __restrict__ Wt4,
                   const float* __restrict__ bias,
                   float* __restrict__ alpha,
                   float* __restrict__ beta,
                   float* __restrict__ kinc) {
    int row = blockIdx.x;            // 0..B*U-1
    int j = threadIdx.x;             // 0..63
    if (j >= 3 * K_) return;
    const float4* h4 = (const float4*)(h_t + (size_t)row * H_);
    float4 a0 = make_float4(0.f, 0.f, 0.f, 0.f);
    float4 a1 = make_float4(0.f, 0.f, 0.f, 0.f);
    #pragma unroll 4
    for (int i = 0; i < H_ / 4; i += 2) {
        float4 hv0 = h4[i];
        float4 wv0 = Wt4[i * (3 * K_) + j];
        float4 hv1 = h4[i + 1];
        float4 wv1 = Wt4[(i + 1) * (3 * K_) + j];
        a0.x += hv0.x * wv0.x; a0.y += hv0.y * wv0.y;
        a0.z += hv0.z * wv0.z; a0.w += hv0.w * wv0.w;
        a1.x += hv1.x * wv1.x; a1.y += hv1.y * wv1.y;
        a1.z += hv1.z * wv1.z; a1.w += hv1.w * wv1.w;
    }
    float dot = (a0.x + a0.y) + (a0.z + a0.w) + (a1.x + a1.y) + (a1.z + a1.w);
    float p = __expf(dot + bias[j]);
    int k = j % K_;
    int which = j / K_;
    size_t idx = (size_t)row * K_ + k;
    if (which == 0)      alpha[idx] = p;
    else if (which == 1) beta[idx]  = p;
    else                 kinc[idx]  = 0.2f * p;
}

// ---------------- Kernel 2: kappa = cumsum(kinc, axis=u), in place ----------
// One wave per (b,k): lane l owns u = l*8 .. l*8+7.
__global__ __launch_bounds__(64)
void scan_kernel(float* __restrict__ kinc) {
    int b = blockIdx.x / K_;
    int k = blockIdx.x % K_;
    int lane = threadIdx.x;          // 0..63
    int ubase = lane * 8;
    float v[8];
    float run = 0.f;
    for (int i = 0; i < 8; ++i) {
        float x = kinc[((size_t)(b * U_) + ubase + i) * K_ + k];
        run += x;
        v[i] = run;                  // inclusive within lane
    }
    float tot = run;
    float x = tot;
    for (int d = 1; d < 64; d <<= 1) {
        float y = __shfl_up(x, d, 64);
        if (lane >= d) x += y;
    }
    float excl = x - tot;            // exclusive prefix of lane totals
    for (int i = 0; i < 8; ++i)
        kinc[((size_t)(b * U_) + ubase + i) * K_ + k] = v[i] + excl;
}

// ---------------- Kernel 3: phi + masked matmul -----------------
// Block = 128 threads handles (b, 8 u-rows). Skips t-chunks where all
// Gaussian terms underflow to 0 in f32 (beta*(kappa-t)^2 > 88).
__global__ __launch_bounds__(AT_THREADS)
void attend_kernel(const float* __restrict__ alpha,
                   const float* __restrict__ beta,
                   const float* __restrict__ kappa,
                   const float* __restrict__ ctx,
                   const float* __restrict__ mask,
                   float* __restrict__ out) {
    __shared__ float a_s[UT][K_], b_s[UT][K_], k_s[UT][K_];
    __shared__ float phi_s[UT][TC + 1];       // +1 pad
    __shared__ float ctx_s[TC][D_];           // 32 KB
    __shared__ float red_lo[AT_THREADS], red_hi[AT_THREADS];

    int tid = threadIdx.x;
    int b = blockIdx.y;
    int u0 = blockIdx.x * UT;

    // load per-u params, compute active-t bounds
    float lo = 1e30f, hi = -1e30f;
    if (tid < UT * K_) {
        int u_l = tid / K_, k = tid % K_;
        size_t idx = ((size_t)(b * U_) + u0 + u_l) * K_ + k;
        float av = alpha[idx], bv = beta[idx], kv = kappa[idx];
        a_s[u_l][k] = av; b_s[u_l][k] = bv; k_s[u_l][k] = kv;
        float r = sqrtf(88.f / bv);
        lo = kv - r; hi = kv + r;
    }
    red_lo[tid] = lo; red_hi[tid] = hi;
    __syncthreads();
    for (int s = AT_THREADS / 2; s > 0; s >>= 1) {
        if (tid < s) {
            red_lo[tid] = fminf(red_lo[tid], red_lo[tid + s]);
            red_hi[tid] = fmaxf(red_hi[tid], red_hi[tid + s]);
        }
        __syncthreads();
    }
    float tile_lo = red_lo[0], tile_hi = red_hi[0];
    int t_begin = max(0, (int)floorf(tile_lo));
    int t_end   = min(T_, (int)ceilf(tile_hi) + 1);
    t_begin = (t_begin / TC) * TC;

    // thread -> (u row, d columns {4g..4g+3} U {64+4g..64+4g+3})
    int u_l = tid >> 4;   // 0..7
    int g   = tid & 15;   // 0..15
    float acc[8];
    #pragma unroll
    for (int i = 0; i < 8; ++i) acc[i] = 0.f;

    for (int t0 = t_begin; t0 < t_end; t0 += TC) {
        __syncthreads();  // protect phi_s/ctx_s from previous iteration's readers
        // stage ctx chunk (coalesced float4)
        {
            const float4* src = (const float4*)(ctx + (((size_t)b * T_ + t0) * D_));
            float4* dst = (float4*)(&ctx_s[0][0]);
            #pragma unroll
            for (int i = 0; i < (TC * D_ / 4) / AT_THREADS; ++i)
                dst[tid + AT_THREADS * i] = src[tid + AT_THREADS * i];
        }
        // phi for this chunk: UT x 64 values, 4 per thread
        #pragma unroll
        for (int i = 0; i < 4; ++i) {
            int lin = tid + AT_THREADS * i;
            int uu = lin >> 6;        // whole wave shares uu -> broadcast param reads
            int tl = lin & 63;
            float tf = (float)(t0 + tl);
            float ph = 0.f;
            #pragma unroll
            for (int k = 0; k < K_; ++k) {
                float d = k_s[uu][k] - tf;
                float x = b_s[uu][k] * d * d;
                ph += a_s[uu][k] * __expf(-x);
            }
            phi_s[uu][tl] = ph * mask[(size_t)b * T_ + t0 + tl];
        }
        __syncthreads();
        // matmul: acc += phi * ctx
        for (int tl = 0; tl < TC; ++tl) {
            float ph = phi_s[u_l][tl];
            const float4* c = (const float4*)(&ctx_s[tl][0]);
            float4 c0 = c[g];         // d = 4g..4g+3
            float4 c1 = c[g + 16];    // d = 64+4g..64+4g+3
            acc[0] += ph * c0.x; acc[1] += ph * c0.y;
            acc[2] += ph * c0.z; acc[3] += ph * c0.w;
            acc[4] += ph * c1.x; acc[5] += ph * c1.y;
            acc[6] += ph * c1.z; acc[7] += ph * c1.w;
        }
    }

    // write out (every element written every launch, even if all-zero)
    float* orow = out + ((size_t)b * U_ + u0 + u_l) * D_;
    *(float4*)(orow + 4 * g)      = make_float4(acc[0], acc[1], acc[2], acc[3]);
    *(float4*)(orow + 64 + 4 * g) = make_float4(acc[4], acc[5], acc[6], acc[7]);
}

extern "C" void kernel_launch(void* const* d_in, const int* in_sizes, int n_in,
                              void* d_out, int out_size, void* d_ws, size_t ws_size,
                              hipStream_t stream) {
    const float* h_t  = (const float*)d_in[0];
    const float* ctx  = (const float*)d_in[1];
    const float* mask = (const float*)d_in[2];
    const float* W    = (const float*)d_in[3];
    const float* bias = (const float*)d_in[4];
    float* out = (float*)d_out;

    const size_t NPARAM = (size_t)B_ * U_ * K_;   // 40960 floats
    float* alpha = (float*)d_ws;
    float* beta  = alpha + NPARAM;
    float* kinc  = beta + NPARAM;                 // becomes kappa after scan
    float4* Wt4  = (float4*)(kinc + NPARAM);      // (H/4)*30 float4 = 61 KB

    wtrans_kernel<<<dim3(15), dim3(256), 0, stream>>>(W, Wt4);
    params_kernel<<<dim3(B_ * U_), dim3(64), 0, stream>>>(h_t, Wt4, bias, alpha, beta, kinc);
    scan_kernel<<<dim3(B_ * K_), dim3(64), 0, stream>>>(kinc);
    attend_kernel<<<dim3(U_ / UT, B_), dim3(AT_THREADS), 0, stream>>>(alpha, beta, kinc, ctx, mask, out);
}